// Round 15
// baseline (173.626 us; speedup 1.0000x reference)
//
#include <hip/hip_runtime.h>
#include <hip/hip_bf16.h>
#include <stdint.h>

typedef __attribute__((ext_vector_type(4))) int i32x4;
typedef __attribute__((ext_vector_type(4))) float f32x4;

#define GLOAD(g, l) __builtin_amdgcn_global_load_lds(                      \
    (const __attribute__((address_space(1))) void*)(g),                    \
    (__attribute__((address_space(3))) void*)(l), 16, 0, 0)

#define MFMAI8 __builtin_amdgcn_mfma_i32_16x16x64_i8
#define BARRIER __builtin_amdgcn_s_barrier

// ---- 256x256x128 8-wave 8-phase i8 GEMM, read-hoisted pipeline ----------
// (K-loop byte-identical to round 12/14. C stored NONTEMPORAL so the
//  131 MB/dispatch write stream doesn't evict the L3-resident A/B panels
//  -- r14 showed FETCH=147MB vs 48MB unique, a 3x refetch.)
__global__ __launch_bounds__(512, 2) void gemm_i8_kernel(
    const char* __restrict__ A,  // [8192][4096] i8
    const char* __restrict__ B,  // [4096][4096] i8 sign
    const float* __restrict__ partials, const float* __restrict__ qrow,
    float* __restrict__ C) {
  constexpr int M = 8192, N = 4096, K = 4096;
  constexpr int NT = K / 128;  // 32 K-steps
  constexpr int NI = NT / 2;   // 16 iterations
  __shared__ __align__(16) char lds[131072];  // 8 slots x 16 KiB

  const int tid = threadIdx.x;
  const int wid = tid >> 6;
  const int lane = tid & 63;
  const int wr = wid >> 2;            // 0..1 : A half (M-rows)
  const int wc = wid & 3;             // 0..3 : 64-col group
  const int bh = wc >> 1;             // B half slot
  const int bsub = (wc & 1) * 8192;   // 64-row band within B half (bytes)
  const int fr = lane & 15;
  const int fq = lane >> 4;
  const int sk0 = ((fq) ^ (fr & 7)) * 16;
  const int sk1 = ((4 + fq) ^ (fr & 7)) * 16;

  const int bid = blockIdx.x;
  const int swz = (bid & 7) * 64 + (bid >> 3);
  const int tm = swz >> 4, tn = swz & 15;

  const int srow = tid >> 3;
  const int sg = (tid & 7) ^ (srow & 7);
  const char* aSrc0 = A + (size_t)(tm * 256 + srow) * K + sg * 16;
  const char* aSrc1 = aSrc0 + (size_t)128 * K;
  const char* bSrc0 = B + (size_t)(tn * 256 + srow) * K + sg * 16;
  const char* bSrc1 = bSrc0 + (size_t)128 * K;

#define STAGE(srcBase, slotIdx, koff)                              \
  do {                                                             \
    const char* _s = (srcBase) + (koff);                           \
    char* _d = lds + (slotIdx) * 16384 + wid * 1024;               \
    GLOAD(_s, _d);                                                 \
    GLOAD(_s + (size_t)64 * K, _d + 8192);                         \
  } while (0)

  const char* aSp0 = lds + (0 + wr) * 16384 + fr * 128;
  const char* aSp1 = lds + (2 + wr) * 16384 + fr * 128;
  const char* bSp0 = lds + (4 + bh) * 16384 + bsub + fr * 128;
  const char* bSp1 = lds + (6 + bh) * 16384 + bsub + fr * 128;

  i32x4 acc[8][4];
#pragma unroll
  for (int m = 0; m < 8; ++m)
#pragma unroll
    for (int n = 0; n < 4; ++n) acc[m][n] = (i32x4){0, 0, 0, 0};

#define RD_B(bS)                                                       \
  _Pragma("unroll") for (int n = 0; n < 4; ++n) {                      \
    bq[n][0] = *(const i32x4*)((bS) + n * 2048 + sk0);                 \
    bq[n][1] = *(const i32x4*)((bS) + n * 2048 + sk1);                 \
  }
#define RD_A(dst, aS, q)                                               \
  _Pragma("unroll") for (int m2 = 0; m2 < 2; ++m2) {                   \
    dst[m2][0] = *(const i32x4*)((aS) + (2 * (q) + m2) * 2048 + sk0);  \
    dst[m2][1] = *(const i32x4*)((aS) + (2 * (q) + m2) * 2048 + sk1);  \
  }
#define QMFMA(av, q)                                                   \
  do {                                                                 \
    __builtin_amdgcn_s_setprio(1);                                     \
    _Pragma("unroll") for (int m2 = 0; m2 < 2; ++m2)                   \
        _Pragma("unroll") for (int n = 0; n < 4; ++n) {                \
      acc[2 * (q) + m2][n] =                                           \
          MFMAI8(av[m2][0], bq[n][0], acc[2 * (q) + m2][n], 0, 0, 0);  \
      acc[2 * (q) + m2][n] =                                           \
          MFMAI8(av[m2][1], bq[n][1], acc[2 * (q) + m2][n], 0, 0, 0);  \
    }                                                                  \
    __builtin_amdgcn_s_setprio(0);                                     \
  } while (0)

  STAGE(bSrc0, 4, 0);
  STAGE(bSrc1, 5, 0);
  STAGE(aSrc0, 0, 0);
  STAGE(aSrc1, 1, 0);
  STAGE(bSrc0, 6, 128);
  asm volatile("s_waitcnt vmcnt(2)" ::: "memory");
  BARRIER();

  i32x4 bq[4][2], av0[2][2], av1[2][2];
  RD_B(bSp0);
  RD_A(av0, aSp0, 0);

  for (int i = 0; i < NI; ++i) {
    const int t0 = 2 * i;
    const int k1 = (t0 + 1) * 128, k2 = (t0 + 2) * 128, k3 = (t0 + 3) * 128;

    // ---- Ph0: issue A q1; stage B1(t0+1)->s7; MFMA q0 ----
    RD_A(av1, aSp0, 1);
    STAGE(bSrc1, 7, k1);
    BARRIER();
    QMFMA(av0, 0);

    // ---- Ph1: issue A q2; stage A0(t0+1)->s2; MFMA q1 ----
    RD_A(av0, aSp0, 2);
    STAGE(aSrc0, 2, k1);
    BARRIER();
    QMFMA(av1, 1);

    // ---- Ph2: issue A q3; stage A1(t0+1)->s3; MFMA q2 ----
    RD_A(av1, aSp0, 3);
    STAGE(aSrc1, 3, k1);
    BARRIER();
    QMFMA(av0, 2);

    // ---- Ph3: stage B0(t0+2)->s4; GATE step t0+1; MFMA q3;
    //      then issue step t0+1's B + A q0 (post-barrier) ----
    if (t0 + 2 < NT) {
      STAGE(bSrc0, 4, k2);
      asm volatile("s_waitcnt vmcnt(2)" ::: "memory");
    } else {
      asm volatile("s_waitcnt vmcnt(0)" ::: "memory");
    }
    BARRIER();
    QMFMA(av1, 3);
    RD_B(bSp1);
    RD_A(av0, aSp1, 0);

    // ---- Ph4: issue A q1; stage B1(t0+2)->s5; MFMA q0 ----
    RD_A(av1, aSp1, 1);
    if (t0 + 2 < NT) STAGE(bSrc1, 5, k2);
    BARRIER();
    QMFMA(av0, 0);

    // ---- Ph5: issue A q2; stage A0(t0+2)->s0; MFMA q1 ----
    RD_A(av0, aSp1, 2);
    if (t0 + 2 < NT) STAGE(aSrc0, 0, k2);
    BARRIER();
    QMFMA(av1, 1);

    // ---- Ph6: issue A q3; stage A1(t0+2)->s1; MFMA q2 ----
    RD_A(av1, aSp1, 3);
    if (t0 + 2 < NT) STAGE(aSrc1, 1, k2);
    BARRIER();
    QMFMA(av0, 2);

    // ---- Ph7: stage B0(t0+3)->s6; GATE step t0+2; MFMA q3;
    //      then issue step t0+2's B + A q0 ----
    if (t0 + 2 < NT) {
      STAGE(bSrc0, 6, k3);
      asm volatile("s_waitcnt vmcnt(2)" ::: "memory");
    }
    BARRIER();
    QMFMA(av1, 3);
    if (t0 + 2 < NT) {
      RD_B(bSp0);
      RD_A(av0, aSp0, 0);
    }
  }

  // ---- epilogue: per-block scale reduce (fixed order, bit-identical
  //      across blocks), then nontemporal C = scale_w * qrow[row] * acc ----
  BARRIER();  // all LDS reads of the K-loop drained block-wide
  float s = 0.f;
  for (int i = tid; i < 4096; i += 512) s += partials[i];  // 8 per thread
#pragma unroll
  for (int off = 32; off > 0; off >>= 1) s += __shfl_down(s, off, 64);
  float* smf = reinterpret_cast<float*>(lds);
  if (lane == 0) smf[wid] = s;
  BARRIER();
  float tot = 0.f;
#pragma unroll
  for (int j = 0; j < 8; ++j) tot += smf[j];
  const float sc = tot * (1.0f / 16777216.0f);

  const int crow0 = tm * 256 + wr * 128 + fq * 4;
  const int ccol0 = tn * 256 + wc * 64 + fr;
#pragma unroll
  for (int m = 0; m < 8; ++m) {
    const int row = crow0 + m * 16;
    float q[4];
#pragma unroll
    for (int j = 0; j < 4; ++j) q[j] = sc * qrow[row + j];
#pragma unroll
    for (int n = 0; n < 4; ++n) {
      i32x4 v = acc[m][n];
      float* cp = C + (size_t)row * N + ccol0 + n * 16;
#pragma unroll
      for (int j = 0; j < 4; ++j)
        __builtin_nontemporal_store((float)v[j] * q[j], cp + (size_t)j * N);
    }
  }
#undef STAGE
#undef RD_A
#undef RD_B
#undef QMFMA
}

// ---- fused prep: blocks 0..8191 = xquant rows; 8192..12287 = wsign ------
// X/W read nontemporal (stream-once); XQ/SQ written normally (want L3).
__global__ __launch_bounds__(256) void prep_kernel(
    const float* __restrict__ X, const float* __restrict__ W,
    char* __restrict__ XQ, char* __restrict__ SQ,
    float* __restrict__ qrow, float* __restrict__ partials) {
  const int b = blockIdx.x;
  const int tid = threadIdx.x;
  if (b < 8192) {
    // ---- xquant: one row, per-row amax -> i8 ----
    const int row = b;
    const f32x4* xr =
        reinterpret_cast<const f32x4*>(X + (size_t)row * 4096);
    int* xo = reinterpret_cast<int*>(XQ + (size_t)row * 4096);
    f32x4 v[4];
    float am = 0.f;
#pragma unroll
    for (int i = 0; i < 4; ++i) {
      v[i] = __builtin_nontemporal_load(xr + tid + 256 * i);
      am = fmaxf(am, fmaxf(fmaxf(fabsf(v[i][0]), fabsf(v[i][1])),
                           fmaxf(fabsf(v[i][2]), fabsf(v[i][3]))));
    }
#pragma unroll
    for (int off = 1; off < 64; off <<= 1)
      am = fmaxf(am, __shfl_xor(am, off, 64));
    __shared__ float wm[4];
    if ((tid & 63) == 0) wm[tid >> 6] = am;
    __syncthreads();
    float amax = fmaxf(fmaxf(wm[0], wm[1]), fmaxf(wm[2], wm[3]));
    amax = fmaxf(amax, 1e-20f);
    const float rq = 127.f / amax;
#pragma unroll
    for (int i = 0; i < 4; ++i) {
      int b0 = __float2int_rn(v[i][0] * rq);
      int b1 = __float2int_rn(v[i][1] * rq);
      int b2 = __float2int_rn(v[i][2] * rq);
      int b3 = __float2int_rn(v[i][3] * rq);
      xo[tid + 256 * i] = (b0 & 255) | ((b1 & 255) << 8) |
                          ((b2 & 255) << 16) | ((b3 & 255) << 24);
    }
    if (tid == 0) qrow[row] = amax * (1.f / 127.f);
  } else {
    // ---- wsign: sign(W) -> i8, partial |W| sums ----
    const int base = (b - 8192) * 1024;
    const f32x4* wp = reinterpret_cast<const f32x4*>(W);
    int* sp = reinterpret_cast<int*>(SQ);
    float s = 0.f;
#pragma unroll
    for (int i = 0; i < 4; ++i) {
      const int idx = base + tid + 256 * i;
      f32x4 w = __builtin_nontemporal_load(wp + idx);
      int b0 = (w[0] > 0.f) - (w[0] < 0.f);
      int b1 = (w[1] > 0.f) - (w[1] < 0.f);
      int b2 = (w[2] > 0.f) - (w[2] < 0.f);
      int b3 = (w[3] > 0.f) - (w[3] < 0.f);
      sp[idx] = (b0 & 255) | ((b1 & 255) << 8) | ((b2 & 255) << 16) |
                ((b3 & 255) << 24);
      s += fabsf(w[0]) + fabsf(w[1]) + fabsf(w[2]) + fabsf(w[3]);
    }
#pragma unroll
    for (int off = 32; off > 0; off >>= 1) s += __shfl_down(s, off, 64);
    __shared__ float sm[4];
    if ((tid & 63) == 0) sm[tid >> 6] = s;
    __syncthreads();
    if (tid == 0) partials[b - 8192] = sm[0] + sm[1] + sm[2] + sm[3];
  }
}

extern "C" void kernel_launch(void* const* d_in, const int* in_sizes, int n_in,
                              void* d_out, int out_size, void* d_ws,
                              size_t ws_size, hipStream_t stream) {
  const float* x = (const float*)d_in[0];   // [8192][4096] f32
  const float* w = (const float*)d_in[1];   // [4096][4096] f32
  float* out = (float*)d_out;               // [8192][4096] f32

  char* ws = (char*)d_ws;
  char* xq = ws;                                   // 32 MiB
  char* sq = ws + 33554432;                        // 16 MiB
  float* qrow = (float*)(ws + 50331648);           // 8192 f32
  float* partials = (float*)(ws + 50331648 + 32768);  // 4096 f32

  prep_kernel<<<12288, 256, 0, stream>>>(x, w, xq, sq, qrow, partials);
  gemm_i8_kernel<<<512, 512, 0, stream>>>(xq, sq, partials, qrow, out);
}

// Round 16
// 161.400 us; speedup vs baseline: 1.0758x; 1.0758x over previous
//
#include <hip/hip_runtime.h>
#include <hip/hip_bf16.h>
#include <stdint.h>

typedef __attribute__((ext_vector_type(4))) int i32x4;
typedef __attribute__((ext_vector_type(4))) float f32x4;

#define GLOAD(g, l) __builtin_amdgcn_global_load_lds(                      \
    (const __attribute__((address_space(1))) void*)(g),                    \
    (__attribute__((address_space(3))) void*)(l), 16, 0, 0)

#define MFMAI8 __builtin_amdgcn_mfma_i32_16x16x64_i8
#define BARRIER __builtin_amdgcn_s_barrier

// ---- 256x256x128 8-wave 8-phase i8 GEMM, read-hoisted pipeline ----------
// (K-loop byte-identical to round 12/14. C stores back to NORMAL (r15: NT
//  stores inflated WRITE 131->180MB, no FETCH gain). Swizzle changed to
//  SQUARE 8x8 tile regions per XCD: per-XCD footprint A8+B8=16MB vs the
//  old 4x16 strip's A4+B16=20MB -- halves the per-XCD B stream.)
__global__ __launch_bounds__(512, 2) void gemm_i8_kernel(
    const char* __restrict__ A,  // [8192][4096] i8
    const char* __restrict__ B,  // [4096][4096] i8 sign
    const float* __restrict__ partials, const float* __restrict__ qrow,
    float* __restrict__ C) {
  constexpr int M = 8192, N = 4096, K = 4096;
  constexpr int NT = K / 128;  // 32 K-steps
  constexpr int NI = NT / 2;   // 16 iterations
  __shared__ __align__(16) char lds[131072];  // 8 slots x 16 KiB

  const int tid = threadIdx.x;
  const int wid = tid >> 6;
  const int lane = tid & 63;
  const int wr = wid >> 2;            // 0..1 : A half (M-rows)
  const int wc = wid & 3;             // 0..3 : 64-col group
  const int bh = wc >> 1;             // B half slot
  const int bsub = (wc & 1) * 8192;   // 64-row band within B half (bytes)
  const int fr = lane & 15;
  const int fq = lane >> 4;
  const int sk0 = ((fq) ^ (fr & 7)) * 16;
  const int sk1 = ((4 + fq) ^ (fr & 7)) * 16;

  // square XCD regions: xcd -> (rm = xcd>>1, rn = xcd&1); 8x8 tiles each
  const int bid = blockIdx.x;
  const int xcd = bid & 7;
  const int local = bid >> 3;          // 0..63
  const int tm = (xcd >> 1) * 8 + (local >> 3);
  const int tn = (xcd & 1) * 8 + (local & 7);

  const int srow = tid >> 3;
  const int sg = (tid & 7) ^ (srow & 7);
  const char* aSrc0 = A + (size_t)(tm * 256 + srow) * K + sg * 16;
  const char* aSrc1 = aSrc0 + (size_t)128 * K;
  const char* bSrc0 = B + (size_t)(tn * 256 + srow) * K + sg * 16;
  const char* bSrc1 = bSrc0 + (size_t)128 * K;

#define STAGE(srcBase, slotIdx, koff)                              \
  do {                                                             \
    const char* _s = (srcBase) + (koff);                           \
    char* _d = lds + (slotIdx) * 16384 + wid * 1024;               \
    GLOAD(_s, _d);                                                 \
    GLOAD(_s + (size_t)64 * K, _d + 8192);                         \
  } while (0)

  const char* aSp0 = lds + (0 + wr) * 16384 + fr * 128;
  const char* aSp1 = lds + (2 + wr) * 16384 + fr * 128;
  const char* bSp0 = lds + (4 + bh) * 16384 + bsub + fr * 128;
  const char* bSp1 = lds + (6 + bh) * 16384 + bsub + fr * 128;

  i32x4 acc[8][4];
#pragma unroll
  for (int m = 0; m < 8; ++m)
#pragma unroll
    for (int n = 0; n < 4; ++n) acc[m][n] = (i32x4){0, 0, 0, 0};

#define RD_B(bS)                                                       \
  _Pragma("unroll") for (int n = 0; n < 4; ++n) {                      \
    bq[n][0] = *(const i32x4*)((bS) + n * 2048 + sk0);                 \
    bq[n][1] = *(const i32x4*)((bS) + n * 2048 + sk1);                 \
  }
#define RD_A(dst, aS, q)                                               \
  _Pragma("unroll") for (int m2 = 0; m2 < 2; ++m2) {                   \
    dst[m2][0] = *(const i32x4*)((aS) + (2 * (q) + m2) * 2048 + sk0);  \
    dst[m2][1] = *(const i32x4*)((aS) + (2 * (q) + m2) * 2048 + sk1);  \
  }
#define QMFMA(av, q)                                                   \
  do {                                                                 \
    __builtin_amdgcn_s_setprio(1);                                     \
    _Pragma("unroll") for (int m2 = 0; m2 < 2; ++m2)                   \
        _Pragma("unroll") for (int n = 0; n < 4; ++n) {                \
      acc[2 * (q) + m2][n] =                                           \
          MFMAI8(av[m2][0], bq[n][0], acc[2 * (q) + m2][n], 0, 0, 0);  \
      acc[2 * (q) + m2][n] =                                           \
          MFMAI8(av[m2][1], bq[n][1], acc[2 * (q) + m2][n], 0, 0, 0);  \
    }                                                                  \
    __builtin_amdgcn_s_setprio(0);                                     \
  } while (0)

  STAGE(bSrc0, 4, 0);
  STAGE(bSrc1, 5, 0);
  STAGE(aSrc0, 0, 0);
  STAGE(aSrc1, 1, 0);
  STAGE(bSrc0, 6, 128);
  asm volatile("s_waitcnt vmcnt(2)" ::: "memory");
  BARRIER();

  i32x4 bq[4][2], av0[2][2], av1[2][2];
  RD_B(bSp0);
  RD_A(av0, aSp0, 0);

  for (int i = 0; i < NI; ++i) {
    const int t0 = 2 * i;
    const int k1 = (t0 + 1) * 128, k2 = (t0 + 2) * 128, k3 = (t0 + 3) * 128;

    // ---- Ph0: issue A q1; stage B1(t0+1)->s7; MFMA q0 ----
    RD_A(av1, aSp0, 1);
    STAGE(bSrc1, 7, k1);
    BARRIER();
    QMFMA(av0, 0);

    // ---- Ph1: issue A q2; stage A0(t0+1)->s2; MFMA q1 ----
    RD_A(av0, aSp0, 2);
    STAGE(aSrc0, 2, k1);
    BARRIER();
    QMFMA(av1, 1);

    // ---- Ph2: issue A q3; stage A1(t0+1)->s3; MFMA q2 ----
    RD_A(av1, aSp0, 3);
    STAGE(aSrc1, 3, k1);
    BARRIER();
    QMFMA(av0, 2);

    // ---- Ph3: stage B0(t0+2)->s4; GATE step t0+1; MFMA q3;
    //      then issue step t0+1's B + A q0 (post-barrier) ----
    if (t0 + 2 < NT) {
      STAGE(bSrc0, 4, k2);
      asm volatile("s_waitcnt vmcnt(2)" ::: "memory");
    } else {
      asm volatile("s_waitcnt vmcnt(0)" ::: "memory");
    }
    BARRIER();
    QMFMA(av1, 3);
    RD_B(bSp1);
    RD_A(av0, aSp1, 0);

    // ---- Ph4: issue A q1; stage B1(t0+2)->s5; MFMA q0 ----
    RD_A(av1, aSp1, 1);
    if (t0 + 2 < NT) STAGE(bSrc1, 5, k2);
    BARRIER();
    QMFMA(av0, 0);

    // ---- Ph5: issue A q2; stage A0(t0+2)->s0; MFMA q1 ----
    RD_A(av0, aSp1, 2);
    if (t0 + 2 < NT) STAGE(aSrc0, 0, k2);
    BARRIER();
    QMFMA(av1, 1);

    // ---- Ph6: issue A q3; stage A1(t0+2)->s1; MFMA q2 ----
    RD_A(av1, aSp1, 3);
    if (t0 + 2 < NT) STAGE(aSrc1, 1, k2);
    BARRIER();
    QMFMA(av0, 2);

    // ---- Ph7: stage B0(t0+3)->s6; GATE step t0+2; MFMA q3;
    //      then issue step t0+2's B + A q0 ----
    if (t0 + 2 < NT) {
      STAGE(bSrc0, 6, k3);
      asm volatile("s_waitcnt vmcnt(2)" ::: "memory");
    }
    BARRIER();
    QMFMA(av1, 3);
    if (t0 + 2 < NT) {
      RD_B(bSp0);
      RD_A(av0, aSp0, 0);
    }
  }

  // ---- epilogue: per-block scale reduce (fixed order, bit-identical
  //      across blocks), then C = scale_w * qrow[row] * acc ----
  BARRIER();  // all LDS reads of the K-loop drained block-wide
  float s = 0.f;
  for (int i = tid; i < 4096; i += 512) s += partials[i];  // 8 per thread
#pragma unroll
  for (int off = 32; off > 0; off >>= 1) s += __shfl_down(s, off, 64);
  float* smf = reinterpret_cast<float*>(lds);
  if (lane == 0) smf[wid] = s;
  BARRIER();
  float tot = 0.f;
#pragma unroll
  for (int j = 0; j < 8; ++j) tot += smf[j];
  const float sc = tot * (1.0f / 16777216.0f);

  const int crow0 = tm * 256 + wr * 128 + fq * 4;
  const int ccol0 = tn * 256 + wc * 64 + fr;
#pragma unroll
  for (int m = 0; m < 8; ++m) {
    const int row = crow0 + m * 16;
    float q[4];
#pragma unroll
    for (int j = 0; j < 4; ++j) q[j] = sc * qrow[row + j];
#pragma unroll
    for (int n = 0; n < 4; ++n) {
      i32x4 v = acc[m][n];
      float* cp = C + (size_t)row * N + ccol0 + n * 16;
#pragma unroll
      for (int j = 0; j < 4; ++j) cp[(size_t)j * N] = (float)v[j] * q[j];
    }
  }
#undef STAGE
#undef RD_A
#undef RD_B
#undef QMFMA
}

// ---- fused prep: blocks 0..8191 = xquant rows; 8192..12287 = wsign ------
// X/W read nontemporal (stream-once); XQ/SQ written normally (want L3).
__global__ __launch_bounds__(256) void prep_kernel(
    const float* __restrict__ X, const float* __restrict__ W,
    char* __restrict__ XQ, char* __restrict__ SQ,
    float* __restrict__ qrow, float* __restrict__ partials) {
  const int b = blockIdx.x;
  const int tid = threadIdx.x;
  if (b < 8192) {
    // ---- xquant: one row, per-row amax -> i8 ----
    const int row = b;
    const f32x4* xr =
        reinterpret_cast<const f32x4*>(X + (size_t)row * 4096);
    int* xo = reinterpret_cast<int*>(XQ + (size_t)row * 4096);
    f32x4 v[4];
    float am = 0.f;
#pragma unroll
    for (int i = 0; i < 4; ++i) {
      v[i] = __builtin_nontemporal_load(xr + tid + 256 * i);
      am = fmaxf(am, fmaxf(fmaxf(fabsf(v[i][0]), fabsf(v[i][1])),
                           fmaxf(fabsf(v[i][2]), fabsf(v[i][3]))));
    }
#pragma unroll
    for (int off = 1; off < 64; off <<= 1)
      am = fmaxf(am, __shfl_xor(am, off, 64));
    __shared__ float wm[4];
    if ((tid & 63) == 0) wm[tid >> 6] = am;
    __syncthreads();
    float amax = fmaxf(fmaxf(wm[0], wm[1]), fmaxf(wm[2], wm[3]));
    amax = fmaxf(amax, 1e-20f);
    const float rq = 127.f / amax;
#pragma unroll
    for (int i = 0; i < 4; ++i) {
      int b0 = __float2int_rn(v[i][0] * rq);
      int b1 = __float2int_rn(v[i][1] * rq);
      int b2 = __float2int_rn(v[i][2] * rq);
      int b3 = __float2int_rn(v[i][3] * rq);
      xo[tid + 256 * i] = (b0 & 255) | ((b1 & 255) << 8) |
                          ((b2 & 255) << 16) | ((b3 & 255) << 24);
    }
    if (tid == 0) qrow[row] = amax * (1.f / 127.f);
  } else {
    // ---- wsign: sign(W) -> i8, partial |W| sums ----
    const int base = (b - 8192) * 1024;
    const f32x4* wp = reinterpret_cast<const f32x4*>(W);
    int* sp = reinterpret_cast<int*>(SQ);
    float s = 0.f;
#pragma unroll
    for (int i = 0; i < 4; ++i) {
      const int idx = base + tid + 256 * i;
      f32x4 w = __builtin_nontemporal_load(wp + idx);
      int b0 = (w[0] > 0.f) - (w[0] < 0.f);
      int b1 = (w[1] > 0.f) - (w[1] < 0.f);
      int b2 = (w[2] > 0.f) - (w[2] < 0.f);
      int b3 = (w[3] > 0.f) - (w[3] < 0.f);
      sp[idx] = (b0 & 255) | ((b1 & 255) << 8) | ((b2 & 255) << 16) |
                ((b3 & 255) << 24);
      s += fabsf(w[0]) + fabsf(w[1]) + fabsf(w[2]) + fabsf(w[3]);
    }
#pragma unroll
    for (int off = 32; off > 0; off >>= 1) s += __shfl_down(s, off, 64);
    __shared__ float sm[4];
    if ((tid & 63) == 0) sm[tid >> 6] = s;
    __syncthreads();
    if (tid == 0) partials[b - 8192] = sm[0] + sm[1] + sm[2] + sm[3];
  }
}

extern "C" void kernel_launch(void* const* d_in, const int* in_sizes, int n_in,
                              void* d_out, int out_size, void* d_ws,
                              size_t ws_size, hipStream_t stream) {
  const float* x = (const float*)d_in[0];   // [8192][4096] f32
  const float* w = (const float*)d_in[1];   // [4096][4096] f32
  float* out = (float*)d_out;               // [8192][4096] f32

  char* ws = (char*)d_ws;
  char* xq = ws;                                   // 32 MiB
  char* sq = ws + 33554432;                        // 16 MiB
  float* qrow = (float*)(ws + 50331648);           // 8192 f32
  float* partials = (float*)(ws + 50331648 + 32768);  // 4096 f32

  prep_kernel<<<12288, 256, 0, stream>>>(x, w, xq, sq, qrow, partials);
  gemm_i8_kernel<<<512, 512, 0, stream>>>(xq, sq, partials, qrow, out);
}